// Round 2
// baseline (622.161 us; speedup 1.0000x reference)
//
#include <hip/hip_runtime.h>

typedef _Float16 half8 __attribute__((ext_vector_type(8)));
typedef __fp16   pk2   __attribute__((ext_vector_type(2)));
typedef float    f32x4 __attribute__((ext_vector_type(4)));

#define GLOBAL_AS __attribute__((address_space(1)))
#define LDS_AS    __attribute__((address_space(3)))

// Problem constants
static constexpr int Bb = 32;
static constexpr int Nn = 2048;
static constexpr int Dd = 1024;
static constexpr int M  = Bb * Nn;   // 65536 rows of the big GEMM

// ---------------------------------------------------------------------------
// Kernel 1: pack W1 (f32, [d][e] row-major) into tile-ordered f16 "W1TT" so the
// GEMM can stage B tiles with contiguous global_load_lds width=16.
// Layout: tile t = et*32 + kt (8 KB each), unit u in [0,512): q=u>>7, e=u&127,
// unit holds W1[kt*32 + q*8 + j][et*128 + e] for j=0..7 (8 f16 = 16 B).
// ---------------------------------------------------------------------------
__global__ void prep_w1(const float* __restrict__ W1, _Float16* __restrict__ W1TT) {
    int g = blockIdx.x * 256 + threadIdx.x;   // 131072 units total
    int tile = g >> 9;                        // 0..255
    int u = g & 511;
    int et = tile >> 5, kt = tile & 31;
    int q = u >> 7, e = u & 127;
    int d0 = kt * 32 + q * 8;
    int col = et * 128 + e;
    half8 h;
#pragma unroll
    for (int j = 0; j < 8; ++j)
        h[j] = (_Float16)W1[(size_t)(d0 + j) * Dd + col];   // coalesced in e
    *(half8*)(W1TT + (size_t)g * 8) = h;
}

// ---------------------------------------------------------------------------
// Kernel 2: dec[b][e] = sum_d decoder_state[b][d] * W2[d][e]   (32x1024)
// grid (32 b, 16 e-chunks of 64), block 256: 4 d-chunks x 64 e lanes.
// ---------------------------------------------------------------------------
__global__ void dec_kernel(const float* __restrict__ ds, const float* __restrict__ W2,
                           float* __restrict__ dec) {
    __shared__ float part[4][64];
    int b = blockIdx.x, ech = blockIdx.y;
    int tid = threadIdx.x;
    int e = ech * 64 + (tid & 63);
    int dc = tid >> 6;
    float acc = 0.f;
#pragma unroll 4
    for (int d = dc * 256; d < dc * 256 + 256; ++d)
        acc += ds[b * Dd + d] * W2[(size_t)d * Dd + e];   // ds scalarizes; W2 coalesced
    part[dc][tid & 63] = acc;
    __syncthreads();
    if (tid < 64)
        dec[b * Dd + e] = part[0][tid] + part[1][tid] + part[2][tid] + part[3][tid];
}

// ---------------------------------------------------------------------------
// Kernel 3: fused GEMM + tanh + vt-dot.
// Tile 128(m) x 128(e), BK=32, 4 waves each computing a 64x64 quadrant via
// 4x4 grid of v_mfma_f32_16x16x32_f16. A (fp32) converted in-loop via
// cvt_pkrtz; B staged via global_load_lds from pre-packed W1TT.
// Epilogue: u_part[et][m] += sum over this block's 128 e of tanh(c+dec)*vt.
// ---------------------------------------------------------------------------
__global__ __launch_bounds__(256) void gemm_fused(
    const float* __restrict__ A,        // encoded [65536][1024] f32
    const _Float16* __restrict__ W1TT,  // tile-packed f16
    const float* __restrict__ dec,      // [32][1024] f32
    const float* __restrict__ vt,       // [1024] f32
    float* __restrict__ u_part)         // [8][65536] f32
{
    // LDS layouts: unit (q in 0..3, row in 0..127) at offset (q*128+row)*16 B.
    // Fragment ds_read_b128 for 16 consecutive rows -> 2-way bank alias (free).
    __shared__ _Float16 As2[4 * 128 * 8];   // 8 KB
    __shared__ _Float16 Bs2[512 * 8];       // 8 KB
    __shared__ float usum[2][128];

    const int et = blockIdx.x;      // 0..7   (fastest -> stripe-sharing blocks adjacent)
    const int mtile = blockIdx.y;   // 0..511
    const int tid = threadIdx.x;
    const int lane = tid & 63, wid = tid >> 6;
    const int wm = wid & 1, we = wid >> 1;
    const int q = lane >> 4, l15 = lane & 15;

    f32x4 acc[4][4] = {};

    // A staging assignment: thread -> (row = tid>>1, khalf = tid&1): 16 floats.
    const int arow = tid >> 1, khalf = tid & 1;
    const float* aptr = A + (size_t)(mtile * 128 + arow) * Dd + khalf * 16;
    const int q0 = khalf * 2;
    // B staging: wave-call c in {0,1}: unit = (wid*2+c)*64 + lane.
    const _Float16* bbase = W1TT + (size_t)et * 32 * 512 * 8
                            + ((size_t)(wid * 2) * 64 + lane) * 8;
    _Float16* bdst0 = &Bs2[(wid * 2 + 0) * 64 * 8];
    _Float16* bdst1 = &Bs2[(wid * 2 + 1) * 64 * 8];

#pragma unroll 1
    for (int kt = 0; kt < 32; ++kt) {
        // issue B async global->LDS first (stays in flight during A convert)
        const _Float16* bk = bbase + (size_t)kt * 512 * 8;
        __builtin_amdgcn_global_load_lds((const GLOBAL_AS void*)bk,
                                         (LDS_AS void*)bdst0, 16, 0, 0);
        __builtin_amdgcn_global_load_lds((const GLOBAL_AS void*)(bk + 64 * 8),
                                         (LDS_AS void*)bdst1, 16, 0, 0);
        // A: 16 fp32 -> 16 f16 (packed RTZ converts), 2x ds_write_b128
        const float4* ap = (const float4*)(aptr + kt * 32);
        float4 f0 = ap[0], f1 = ap[1], f2 = ap[2], f3 = ap[3];
        half8 h0, h1;
        {
            pk2 t;
            t = __builtin_amdgcn_cvt_pkrtz(f0.x, f0.y); h0[0] = t[0]; h0[1] = t[1];
            t = __builtin_amdgcn_cvt_pkrtz(f0.z, f0.w); h0[2] = t[0]; h0[3] = t[1];
            t = __builtin_amdgcn_cvt_pkrtz(f1.x, f1.y); h0[4] = t[0]; h0[5] = t[1];
            t = __builtin_amdgcn_cvt_pkrtz(f1.z, f1.w); h0[6] = t[0]; h0[7] = t[1];
            t = __builtin_amdgcn_cvt_pkrtz(f2.x, f2.y); h1[0] = t[0]; h1[1] = t[1];
            t = __builtin_amdgcn_cvt_pkrtz(f2.z, f2.w); h1[2] = t[0]; h1[3] = t[1];
            t = __builtin_amdgcn_cvt_pkrtz(f3.x, f3.y); h1[4] = t[0]; h1[5] = t[1];
            t = __builtin_amdgcn_cvt_pkrtz(f3.z, f3.w); h1[6] = t[0]; h1[7] = t[1];
        }
        *(half8*)&As2[((q0 + 0) * 128 + arow) * 8] = h0;
        *(half8*)&As2[((q0 + 1) * 128 + arow) * 8] = h1;
        __syncthreads();   // drains vmcnt (global_load_lds) + lgkm (ds_write)

        half8 af[4], bf[4];
#pragma unroll
        for (int mt = 0; mt < 4; ++mt)
            af[mt] = *(const half8*)&As2[(q * 128 + wm * 64 + mt * 16 + l15) * 8];
#pragma unroll
        for (int nt = 0; nt < 4; ++nt)
            bf[nt] = *(const half8*)&Bs2[(q * 128 + we * 64 + nt * 16 + l15) * 8];
#pragma unroll
        for (int mt = 0; mt < 4; ++mt)
#pragma unroll
            for (int nt = 0; nt < 4; ++nt)
                acc[mt][nt] = __builtin_amdgcn_mfma_f32_16x16x32_f16(
                    af[mt], bf[nt], acc[mt][nt], 0, 0, 0);
        __syncthreads();
    }

    // ---- epilogue: tanh(c + dec) * vt, reduce over this block's 128 cols ----
    const int b = mtile >> 4;   // 128-row tiles align with 2048-row batches
    float vtv[4], dcv[4];
#pragma unroll
    for (int nt = 0; nt < 4; ++nt) {
        int e = et * 128 + we * 64 + nt * 16 + l15;
        vtv[nt] = vt[e];
        dcv[nt] = dec[b * Dd + e];
    }
#pragma unroll
    for (int mt = 0; mt < 4; ++mt) {
#pragma unroll
        for (int r = 0; r < 4; ++r) {
            float s = 0.f;
#pragma unroll
            for (int nt = 0; nt < 4; ++nt) {
                float x = acc[mt][nt][r] + dcv[nt];
                // tanh(x) = 1 - 2/(exp(2x)+1); handles +-inf saturation correctly
                float ex = __expf(2.f * x);
                float th = 1.f - 2.f * __builtin_amdgcn_rcpf(ex + 1.f);
                s += th * vtv[nt];
            }
            // C/D layout: row = mt*16 + q*4 + r (quad-uniform), col = l15.
            // Reduce the 16 lanes of the quad (cols), + nt already summed = 64 cols.
#pragma unroll
            for (int off = 1; off < 16; off <<= 1) s += __shfl_xor(s, off, 16);
            if (l15 == 0) usum[we][wm * 64 + mt * 16 + q * 4 + r] = s;
        }
    }
    __syncthreads();
    if (tid < 128)
        u_part[(size_t)et * M + (size_t)mtile * 128 + tid] = usum[0][tid] + usum[1][tid];
}

// ---------------------------------------------------------------------------
// Kernel 4: masked log-softmax over N=2048 per batch row.
// logits = sum_et u_part + (mask ? 0 : ln(fp32(1e-45))); out = l - max - log(sum exp)
// ---------------------------------------------------------------------------
__global__ void softmax_k(const float* __restrict__ up, const int* __restrict__ mask,
                          float* __restrict__ out) {
    __shared__ float red[8];
    int b = blockIdx.x, tid = threadIdx.x;   // 32 blocks x 256 threads
    float l[8];
#pragma unroll
    for (int i = 0; i < 8; ++i) {
        int n = i * 256 + tid;
        float s = up[(size_t)b * Nn + n];
#pragma unroll
        for (int et = 1; et < 8; ++et) s += up[(size_t)et * M + (size_t)b * Nn + n];
        l[i] = s + (mask[b * Nn + n] ? 0.f : -103.278931f);  // ln(2^-149)
    }
    float m = l[0];
#pragma unroll
    for (int i = 1; i < 8; ++i) m = fmaxf(m, l[i]);
#pragma unroll
    for (int o = 32; o >= 1; o >>= 1) m = fmaxf(m, __shfl_xor(m, o, 64));
    if ((tid & 63) == 0) red[tid >> 6] = m;
    __syncthreads();
    m = fmaxf(fmaxf(red[0], red[1]), fmaxf(red[2], red[3]));
    float s = 0.f;
#pragma unroll
    for (int i = 0; i < 8; ++i) s += expf(l[i] - m);
#pragma unroll
    for (int o = 32; o >= 1; o >>= 1) s += __shfl_xor(s, o, 64);
    if ((tid & 63) == 0) red[4 + (tid >> 6)] = s;
    __syncthreads();
    float lse = m + logf(red[4] + red[5] + red[6] + red[7]);
#pragma unroll
    for (int i = 0; i < 8; ++i)
        out[(size_t)b * Nn + i * 256 + tid] = l[i] - lse;
}

// ---------------------------------------------------------------------------
extern "C" void kernel_launch(void* const* d_in, const int* in_sizes, int n_in,
                              void* d_out, int out_size, void* d_ws, size_t ws_size,
                              hipStream_t stream) {
    const float* encoded = (const float*)d_in[0];   // [32][2048][1024]
    const float* dstate  = (const float*)d_in[1];   // [32][1024]
    const int*   mask    = (const int*)d_in[2];     // [32][2048]
    const float* W1      = (const float*)d_in[3];   // [1024][1024]
    const float* W2      = (const float*)d_in[4];   // [1024][1024]
    const float* vt      = (const float*)d_in[5];   // [1024]
    float* out = (float*)d_out;

    // workspace layout: u_part (2 MiB) | dec (128 KB) | W1TT (2 MiB)
    char* ws = (char*)d_ws;
    float*    u_part = (float*)ws;
    float*    dec    = (float*)(ws + (size_t)8 * M * 4);
    _Float16* W1TT   = (_Float16*)(ws + (size_t)8 * M * 4 + (size_t)Bb * Dd * 4);

    prep_w1<<<512, 256, 0, stream>>>(W1, W1TT);
    dec_kernel<<<dim3(32, 16), 256, 0, stream>>>(dstate, W2, dec);
    gemm_fused<<<dim3(8, 512), 256, 0, stream>>>(encoded, W1TT, dec, vt, u_part);
    softmax_k<<<32, 256, 0, stream>>>(u_part, mask, out);
}

// Round 3
// 619.319 us; speedup vs baseline: 1.0046x; 1.0046x over previous
//
#include <hip/hip_runtime.h>

typedef _Float16 half8 __attribute__((ext_vector_type(8)));
typedef __fp16   pk2   __attribute__((ext_vector_type(2)));
typedef float    f32x4 __attribute__((ext_vector_type(4)));

#define GLOBAL_AS __attribute__((address_space(1)))
#define LDS_AS    __attribute__((address_space(3)))

static constexpr int Bb = 32;
static constexpr int Nn = 2048;
static constexpr int Dd = 1024;
static constexpr int M  = Bb * Nn;   // 65536 rows of the big GEMM

// ---------------------------------------------------------------------------
// Kernel 1a: pack W1 (f32 [d][e]) -> tile-ordered f16 W1TT (as in R2).
// tile t = et*32+kt (8 KB), unit u: q=u>>7,e=u&127 holds W1[kt*32+q*8+j][et*128+e].
// ---------------------------------------------------------------------------
__global__ void prep_w1(const float* __restrict__ W1, _Float16* __restrict__ W1TT) {
    int g = blockIdx.x * 256 + threadIdx.x;   // 131072 units
    int tile = g >> 9;
    int u = g & 511;
    int et = tile >> 5, kt = tile & 31;
    int q = u >> 7, e = u & 127;
    int d0 = kt * 32 + q * 8;
    int col = et * 128 + e;
    half8 h;
#pragma unroll
    for (int j = 0; j < 8; ++j)
        h[j] = (_Float16)W1[(size_t)(d0 + j) * Dd + col];
    *(half8*)(W1TT + (size_t)g * 8) = h;
}

// ---------------------------------------------------------------------------
// Kernel 1b: convert+pack encoded (f32 [m][d]) -> f16 tile order A_p.
// tile t = mtile*32+kt (8 KB = 512 units of 8 f16), unit v: row=v>>2, kc=v&3
// holds A[mtile*128+row][kt*32+kc*8 .. +8]. Write fully coalesced (16 B/thread).
// ---------------------------------------------------------------------------
__global__ void prep_enc(const float* __restrict__ A, _Float16* __restrict__ A_p) {
    int g = blockIdx.x * 256 + threadIdx.x;    // 8388608 units
    int tile = g >> 9;
    int v = g & 511;
    int row = v >> 2, kc = v & 3;
    const float* src = A + ((size_t)(tile >> 5) * 128 + row) * Dd
                         + (tile & 31) * 32 + kc * 8;
    f32x4 f0 = *(const f32x4*)src;
    f32x4 f1 = *(const f32x4*)(src + 4);
    half8 h;
    pk2 t;
    t = __builtin_amdgcn_cvt_pkrtz(f0.x, f0.y); h[0] = t[0]; h[1] = t[1];
    t = __builtin_amdgcn_cvt_pkrtz(f0.z, f0.w); h[2] = t[0]; h[3] = t[1];
    t = __builtin_amdgcn_cvt_pkrtz(f1.x, f1.y); h[4] = t[0]; h[5] = t[1];
    t = __builtin_amdgcn_cvt_pkrtz(f1.z, f1.w); h[6] = t[0]; h[7] = t[1];
    *(half8*)(A_p + (size_t)g * 8) = h;
}

// ---------------------------------------------------------------------------
// Kernel 2: dec[b][e] = decoder_state[b] @ W2   (32x1024)
// ---------------------------------------------------------------------------
__global__ void dec_kernel(const float* __restrict__ ds, const float* __restrict__ W2,
                           float* __restrict__ dec) {
    __shared__ float part[4][64];
    int b = blockIdx.x, ech = blockIdx.y;
    int tid = threadIdx.x;
    int e = ech * 64 + (tid & 63);
    int dc = tid >> 6;
    float acc = 0.f;
#pragma unroll 4
    for (int d = dc * 256; d < dc * 256 + 256; ++d)
        acc += ds[b * Dd + d] * W2[(size_t)d * Dd + e];
    part[dc][tid & 63] = acc;
    __syncthreads();
    if (tid < 64)
        dec[b * Dd + e] = part[0][tid] + part[1][tid] + part[2][tid] + part[3][tid];
}

// ---------------------------------------------------------------------------
// Kernel 3 (fast path): GEMM on pre-packed f16 A and B, all staging via
// global_load_lds width=16 (m97 structure). Epilogue: tanh(c+dec)*vt reduce.
// LDS A layout row-major [128][32] f16 (unit = row*4+kc), fragment read
// As[(row)*32 + q*8] -> ds_read_b128, 8-lane/bank-group minimum passes.
// ---------------------------------------------------------------------------
__global__ __launch_bounds__(256) void gemm_fused_h(
    const _Float16* __restrict__ A_p,   // tile-packed f16 encoded
    const _Float16* __restrict__ W1TT,  // tile-packed f16 W1
    const float* __restrict__ dec,
    const float* __restrict__ vt,
    float* __restrict__ u_part)         // [8][65536]
{
    __shared__ _Float16 As[4096];       // 8 KB
    __shared__ _Float16 Bs[4096];       // 8 KB
    __shared__ float usum[2][128];

    const int et = blockIdx.x;          // 0..7
    const int mtile = blockIdx.y;       // 0..511
    const int tid = threadIdx.x;
    const int lane = tid & 63, wid = tid >> 6;
    const int wm = wid & 1, we = wid >> 1;
    const int q = lane >> 4, l15 = lane & 15;

    f32x4 acc[4][4] = {};

    // staging: wave wid, call c in {0,1}: unit = (wid*2+c)*64 + lane (16 B each)
    const _Float16* abase = A_p + (size_t)mtile * 32 * 4096
                            + ((size_t)(wid * 2) * 64 + lane) * 8;
    const _Float16* bbase = W1TT + (size_t)et * 32 * 4096
                            + ((size_t)(wid * 2) * 64 + lane) * 8;
    _Float16* adst0 = &As[(wid * 2 + 0) * 64 * 8];
    _Float16* adst1 = &As[(wid * 2 + 1) * 64 * 8];
    _Float16* bdst0 = &Bs[(wid * 2 + 0) * 64 * 8];
    _Float16* bdst1 = &Bs[(wid * 2 + 1) * 64 * 8];

#pragma unroll 1
    for (int kt = 0; kt < 32; ++kt) {
        const _Float16* ak = abase + (size_t)kt * 4096;
        const _Float16* bk = bbase + (size_t)kt * 4096;
        __builtin_amdgcn_global_load_lds((const GLOBAL_AS void*)ak,
                                         (LDS_AS void*)adst0, 16, 0, 0);
        __builtin_amdgcn_global_load_lds((const GLOBAL_AS void*)(ak + 64 * 8),
                                         (LDS_AS void*)adst1, 16, 0, 0);
        __builtin_amdgcn_global_load_lds((const GLOBAL_AS void*)bk,
                                         (LDS_AS void*)bdst0, 16, 0, 0);
        __builtin_amdgcn_global_load_lds((const GLOBAL_AS void*)(bk + 64 * 8),
                                         (LDS_AS void*)bdst1, 16, 0, 0);
        __syncthreads();   // drains vmcnt (global_load_lds)

        half8 af[4], bf[4];
#pragma unroll
        for (int mt = 0; mt < 4; ++mt)
            af[mt] = *(const half8*)&As[(wm * 64 + mt * 16 + l15) * 32 + q * 8];
#pragma unroll
        for (int nt = 0; nt < 4; ++nt)
            bf[nt] = *(const half8*)&Bs[(q * 128 + we * 64 + nt * 16 + l15) * 8];
#pragma unroll
        for (int mt = 0; mt < 4; ++mt)
#pragma unroll
            for (int nt = 0; nt < 4; ++nt)
                acc[mt][nt] = __builtin_amdgcn_mfma_f32_16x16x32_f16(
                    af[mt], bf[nt], acc[mt][nt], 0, 0, 0);
        __syncthreads();
    }

    // ---- epilogue: tanh(c + dec) * vt, reduce over this block's 128 cols ----
    const int b = mtile >> 4;
    float vtv[4], dcv[4];
#pragma unroll
    for (int nt = 0; nt < 4; ++nt) {
        int e = et * 128 + we * 64 + nt * 16 + l15;
        vtv[nt] = vt[e];
        dcv[nt] = dec[b * Dd + e];
    }
#pragma unroll
    for (int mt = 0; mt < 4; ++mt) {
#pragma unroll
        for (int r = 0; r < 4; ++r) {
            float s = 0.f;
#pragma unroll
            for (int nt = 0; nt < 4; ++nt) {
                float x = acc[mt][nt][r] + dcv[nt];
                float ex = __expf(2.f * x);
                float th = 1.f - 2.f * __builtin_amdgcn_rcpf(ex + 1.f);
                s += th * vtv[nt];
            }
#pragma unroll
            for (int off = 1; off < 16; off <<= 1) s += __shfl_xor(s, off, 16);
            if (l15 == 0) usum[we][wm * 64 + mt * 16 + q * 4 + r] = s;
        }
    }
    __syncthreads();
    if (tid < 128)
        u_part[(size_t)et * M + (size_t)mtile * 128 + tid] = usum[0][tid] + usum[1][tid];
}

// ---------------------------------------------------------------------------
// Kernel 3 (fallback, R2 path): f32 A with in-loop convert. Used only if
// ws_size can't hold the 128 MB packed A.
// ---------------------------------------------------------------------------
__global__ __launch_bounds__(256) void gemm_fused_f32(
    const float* __restrict__ A, const _Float16* __restrict__ W1TT,
    const float* __restrict__ dec, const float* __restrict__ vt,
    float* __restrict__ u_part)
{
    __shared__ _Float16 As2[4 * 128 * 8];
    __shared__ _Float16 Bs2[512 * 8];
    __shared__ float usum[2][128];

    const int et = blockIdx.x, mtile = blockIdx.y;
    const int tid = threadIdx.x;
    const int lane = tid & 63, wid = tid >> 6;
    const int wm = wid & 1, we = wid >> 1;
    const int q = lane >> 4, l15 = lane & 15;
    f32x4 acc[4][4] = {};

    const int arow = tid >> 1, khalf = tid & 1;
    const float* aptr = A + (size_t)(mtile * 128 + arow) * Dd + khalf * 16;
    const int q0 = khalf * 2;
    const _Float16* bbase = W1TT + (size_t)et * 32 * 4096
                            + ((size_t)(wid * 2) * 64 + lane) * 8;
    _Float16* bdst0 = &Bs2[(wid * 2 + 0) * 64 * 8];
    _Float16* bdst1 = &Bs2[(wid * 2 + 1) * 64 * 8];

#pragma unroll 1
    for (int kt = 0; kt < 32; ++kt) {
        const _Float16* bk = bbase + (size_t)kt * 4096;
        __builtin_amdgcn_global_load_lds((const GLOBAL_AS void*)bk,
                                         (LDS_AS void*)bdst0, 16, 0, 0);
        __builtin_amdgcn_global_load_lds((const GLOBAL_AS void*)(bk + 64 * 8),
                                         (LDS_AS void*)bdst1, 16, 0, 0);
        const float4* ap = (const float4*)(aptr + kt * 32);
        float4 f0 = ap[0], f1 = ap[1], f2 = ap[2], f3 = ap[3];
        half8 h0, h1;
        {
            pk2 t;
            t = __builtin_amdgcn_cvt_pkrtz(f0.x, f0.y); h0[0] = t[0]; h0[1] = t[1];
            t = __builtin_amdgcn_cvt_pkrtz(f0.z, f0.w); h0[2] = t[0]; h0[3] = t[1];
            t = __builtin_amdgcn_cvt_pkrtz(f1.x, f1.y); h0[4] = t[0]; h0[5] = t[1];
            t = __builtin_amdgcn_cvt_pkrtz(f1.z, f1.w); h0[6] = t[0]; h0[7] = t[1];
            t = __builtin_amdgcn_cvt_pkrtz(f2.x, f2.y); h1[0] = t[0]; h1[1] = t[1];
            t = __builtin_amdgcn_cvt_pkrtz(f2.z, f2.w); h1[2] = t[0]; h1[3] = t[1];
            t = __builtin_amdgcn_cvt_pkrtz(f3.x, f3.y); h1[4] = t[0]; h1[5] = t[1];
            t = __builtin_amdgcn_cvt_pkrtz(f3.z, f3.w); h1[6] = t[0]; h1[7] = t[1];
        }
        *(half8*)&As2[((q0 + 0) * 128 + arow) * 8] = h0;
        *(half8*)&As2[((q0 + 1) * 128 + arow) * 8] = h1;
        __syncthreads();

        half8 af[4], bf[4];
#pragma unroll
        for (int mt = 0; mt < 4; ++mt)
            af[mt] = *(const half8*)&As2[(q * 128 + wm * 64 + mt * 16 + l15) * 8];
#pragma unroll
        for (int nt = 0; nt < 4; ++nt)
            bf[nt] = *(const half8*)&Bs2[(q * 128 + we * 64 + nt * 16 + l15) * 8];
#pragma unroll
        for (int mt = 0; mt < 4; ++mt)
#pragma unroll
            for (int nt = 0; nt < 4; ++nt)
                acc[mt][nt] = __builtin_amdgcn_mfma_f32_16x16x32_f16(
                    af[mt], bf[nt], acc[mt][nt], 0, 0, 0);
        __syncthreads();
    }

    const int b = mtile >> 4;
    float vtv[4], dcv[4];
#pragma unroll
    for (int nt = 0; nt < 4; ++nt) {
        int e = et * 128 + we * 64 + nt * 16 + l15;
        vtv[nt] = vt[e];
        dcv[nt] = dec[b * Dd + e];
    }
#pragma unroll
    for (int mt = 0; mt < 4; ++mt) {
#pragma unroll
        for (int r = 0; r < 4; ++r) {
            float s = 0.f;
#pragma unroll
            for (int nt = 0; nt < 4; ++nt) {
                float x = acc[mt][nt][r] + dcv[nt];
                float ex = __expf(2.f * x);
                float th = 1.f - 2.f * __builtin_amdgcn_rcpf(ex + 1.f);
                s += th * vtv[nt];
            }
#pragma unroll
            for (int off = 1; off < 16; off <<= 1) s += __shfl_xor(s, off, 16);
            if (l15 == 0) usum[we][wm * 64 + mt * 16 + q * 4 + r] = s;
        }
    }
    __syncthreads();
    if (tid < 128)
        u_part[(size_t)et * M + (size_t)mtile * 128 + tid] = usum[0][tid] + usum[1][tid];
}

// ---------------------------------------------------------------------------
// Kernel 4: masked log-softmax over N=2048 per batch row.
// ---------------------------------------------------------------------------
__global__ void softmax_k(const float* __restrict__ up, const int* __restrict__ mask,
                          float* __restrict__ out) {
    __shared__ float red[8];
    int b = blockIdx.x, tid = threadIdx.x;
    float l[8];
#pragma unroll
    for (int i = 0; i < 8; ++i) {
        int n = i * 256 + tid;
        float s = up[(size_t)b * Nn + n];
#pragma unroll
        for (int et = 1; et < 8; ++et) s += up[(size_t)et * M + (size_t)b * Nn + n];
        l[i] = s + (mask[b * Nn + n] ? 0.f : -103.278931f);  // ln(2^-149)
    }
    float m = l[0];
#pragma unroll
    for (int i = 1; i < 8; ++i) m = fmaxf(m, l[i]);
#pragma unroll
    for (int o = 32; o >= 1; o >>= 1) m = fmaxf(m, __shfl_xor(m, o, 64));
    if ((tid & 63) == 0) red[tid >> 6] = m;
    __syncthreads();
    m = fmaxf(fmaxf(red[0], red[1]), fmaxf(red[2], red[3]));
    float s = 0.f;
#pragma unroll
    for (int i = 0; i < 8; ++i) s += expf(l[i] - m);
#pragma unroll
    for (int o = 32; o >= 1; o >>= 1) s += __shfl_xor(s, o, 64);
    if ((tid & 63) == 0) red[4 + (tid >> 6)] = s;
    __syncthreads();
    float lse = m + logf(red[4] + red[5] + red[6] + red[7]);
#pragma unroll
    for (int i = 0; i < 8; ++i)
        out[(size_t)b * Nn + i * 256 + tid] = l[i] - lse;
}

// ---------------------------------------------------------------------------
extern "C" void kernel_launch(void* const* d_in, const int* in_sizes, int n_in,
                              void* d_out, int out_size, void* d_ws, size_t ws_size,
                              hipStream_t stream) {
    const float* encoded = (const float*)d_in[0];
    const float* dstate  = (const float*)d_in[1];
    const int*   mask    = (const int*)d_in[2];
    const float* W1      = (const float*)d_in[3];
    const float* W2      = (const float*)d_in[4];
    const float* vt      = (const float*)d_in[5];
    float* out = (float*)d_out;

    // ws layout: u_part (2 MiB) | dec (128 KB) | W1TT (2 MiB) | A_p (128 MiB)
    char* ws = (char*)d_ws;
    float*    u_part = (float*)ws;
    float*    dec    = (float*)(ws + (size_t)8 * M * 4);
    _Float16* W1TT   = (_Float16*)(ws + (size_t)8 * M * 4 + (size_t)Bb * Dd * 4);
    _Float16* A_p    = (_Float16*)(ws + (size_t)8 * M * 4 + (size_t)Bb * Dd * 4
                                   + (size_t)Dd * Dd * 2);
    const size_t needed = (size_t)8 * M * 4 + (size_t)Bb * Dd * 4
                        + (size_t)Dd * Dd * 2 + (size_t)M * Dd * 2;

    prep_w1<<<512, 256, 0, stream>>>(W1, W1TT);
    dec_kernel<<<dim3(32, 16), 256, 0, stream>>>(dstate, W2, dec);
    if (ws_size >= needed) {
        prep_enc<<<32768, 256, 0, stream>>>(encoded, A_p);
        gemm_fused_h<<<dim3(8, 512), 256, 0, stream>>>(A_p, W1TT, dec, vt, u_part);
    } else {
        gemm_fused_f32<<<dim3(8, 512), 256, 0, stream>>>(encoded, W1TT, dec, vt, u_part);
    }
    softmax_k<<<32, 256, 0, stream>>>(u_part, mask, out);
}

// Round 4
// 609.988 us; speedup vs baseline: 1.0200x; 1.0153x over previous
//
#include <hip/hip_runtime.h>

typedef _Float16 half8 __attribute__((ext_vector_type(8)));
typedef __fp16   pk2   __attribute__((ext_vector_type(2)));
typedef float    f32x4 __attribute__((ext_vector_type(4)));

#define GLOBAL_AS __attribute__((address_space(1)))
#define LDS_AS    __attribute__((address_space(3)))

static constexpr int Bb = 32;
static constexpr int Nn = 2048;
static constexpr int Dd = 1024;
static constexpr int M  = Bb * Nn;   // 65536 rows of the big GEMM

// ---------------------------------------------------------------------------
// Kernel 1a: pack W1 (f32 [d][e]) -> tile-ordered f16 W1TT.
// tile t = et*32+kt (8 KB), unit u: q=u>>7,e=u&127 holds W1[kt*32+q*8+j][et*128+e].
// ---------------------------------------------------------------------------
__global__ void prep_w1(const float* __restrict__ W1, _Float16* __restrict__ W1TT) {
    int g = blockIdx.x * 256 + threadIdx.x;   // 131072 units
    int tile = g >> 9;
    int u = g & 511;
    int et = tile >> 5, kt = tile & 31;
    int q = u >> 7, e = u & 127;
    int d0 = kt * 32 + q * 8;
    int col = et * 128 + e;
    half8 h;
#pragma unroll
    for (int j = 0; j < 8; ++j)
        h[j] = (_Float16)W1[(size_t)(d0 + j) * Dd + col];
    *(half8*)(W1TT + (size_t)g * 8) = h;
}

// ---------------------------------------------------------------------------
// Kernel 1b: convert+pack encoded (f32 [m][d]) -> f16 tile order A_p.
// tile t = mtile*32+kt (8 KB = 512 units of 8 f16), unit v: row=v>>2, kc=v&3
// holds A[mtile*128+row][kt*32+kc*8 .. +8]. 16 B/thread, fully coalesced.
// ---------------------------------------------------------------------------
__global__ void prep_enc(const float* __restrict__ A, _Float16* __restrict__ A_p) {
    int g = blockIdx.x * 256 + threadIdx.x;    // 8388608 units
    int tile = g >> 9;
    int v = g & 511;
    int row = v >> 2, kc = v & 3;
    const float* src = A + ((size_t)(tile >> 5) * 128 + row) * Dd
                         + (tile & 31) * 32 + kc * 8;
    f32x4 f0 = *(const f32x4*)src;
    f32x4 f1 = *(const f32x4*)(src + 4);
    half8 h;
    pk2 t;
    t = __builtin_amdgcn_cvt_pkrtz(f0.x, f0.y); h[0] = t[0]; h[1] = t[1];
    t = __builtin_amdgcn_cvt_pkrtz(f0.z, f0.w); h[2] = t[0]; h[3] = t[1];
    t = __builtin_amdgcn_cvt_pkrtz(f1.x, f1.y); h[4] = t[0]; h[5] = t[1];
    t = __builtin_amdgcn_cvt_pkrtz(f1.z, f1.w); h[6] = t[0]; h[7] = t[1];
    *(half8*)(A_p + (size_t)g * 8) = h;
}

// ---------------------------------------------------------------------------
// Kernel 2: dec[b][e] = decoder_state[b] @ W2   (32x1024)
// ---------------------------------------------------------------------------
__global__ void dec_kernel(const float* __restrict__ ds, const float* __restrict__ W2,
                           float* __restrict__ dec) {
    __shared__ float part[4][64];
    int b = blockIdx.x, ech = blockIdx.y;
    int tid = threadIdx.x;
    int e = ech * 64 + (tid & 63);
    int dc = tid >> 6;
    float acc = 0.f;
#pragma unroll 4
    for (int d = dc * 256; d < dc * 256 + 256; ++d)
        acc += ds[b * Dd + d] * W2[(size_t)d * Dd + e];
    part[dc][tid & 63] = acc;
    __syncthreads();
    if (tid < 64)
        dec[b * Dd + e] = part[0][tid] + part[1][tid] + part[2][tid] + part[3][tid];
}

// ---------------------------------------------------------------------------
// Kernel 3 (fast path): GEMM on pre-packed f16 A and B via global_load_lds.
// 1D grid with XCD-aware swizzle: et=(g>>3)&7, mtile=(g&7)+8*(g>>6).
// Same-mtile et-group => block IDs congruent mod 8, within a 64-ID window =>
// same XCD under round-robin dispatch => A stripe fetched into that L2 once.
// ---------------------------------------------------------------------------
__global__ __launch_bounds__(256) void gemm_fused_h(
    const _Float16* __restrict__ A_p,   // tile-packed f16 encoded
    const _Float16* __restrict__ W1TT,  // tile-packed f16 W1
    const float* __restrict__ dec,
    const float* __restrict__ vt,
    float* __restrict__ u_part)         // [8][65536]
{
    __shared__ _Float16 As[4096];       // 8 KB
    __shared__ _Float16 Bs[4096];       // 8 KB
    __shared__ float usum[2][128];

    const int g = blockIdx.x;           // 0..4095
    const int et = (g >> 3) & 7;
    const int mtile = (g & 7) + ((g >> 6) << 3);
    const int tid = threadIdx.x;
    const int lane = tid & 63, wid = tid >> 6;
    const int wm = wid & 1, we = wid >> 1;
    const int q = lane >> 4, l15 = lane & 15;

    f32x4 acc[4][4] = {};

    // staging: wave wid, call c in {0,1}: unit = (wid*2+c)*64 + lane (16 B each)
    const _Float16* abase = A_p + (size_t)mtile * 32 * 4096
                            + ((size_t)(wid * 2) * 64 + lane) * 8;
    const _Float16* bbase = W1TT + (size_t)et * 32 * 4096
                            + ((size_t)(wid * 2) * 64 + lane) * 8;
    _Float16* adst0 = &As[(wid * 2 + 0) * 64 * 8];
    _Float16* adst1 = &As[(wid * 2 + 1) * 64 * 8];
    _Float16* bdst0 = &Bs[(wid * 2 + 0) * 64 * 8];
    _Float16* bdst1 = &Bs[(wid * 2 + 1) * 64 * 8];

#pragma unroll 1
    for (int kt = 0; kt < 32; ++kt) {
        const _Float16* ak = abase + (size_t)kt * 4096;
        const _Float16* bk = bbase + (size_t)kt * 4096;
        __builtin_amdgcn_global_load_lds((const GLOBAL_AS void*)ak,
                                         (LDS_AS void*)adst0, 16, 0, 0);
        __builtin_amdgcn_global_load_lds((const GLOBAL_AS void*)(ak + 64 * 8),
                                         (LDS_AS void*)adst1, 16, 0, 0);
        __builtin_amdgcn_global_load_lds((const GLOBAL_AS void*)bk,
                                         (LDS_AS void*)bdst0, 16, 0, 0);
        __builtin_amdgcn_global_load_lds((const GLOBAL_AS void*)(bk + 64 * 8),
                                         (LDS_AS void*)bdst1, 16, 0, 0);
        __syncthreads();   // drains vmcnt (global_load_lds)

        half8 af[4], bf[4];
#pragma unroll
        for (int mt = 0; mt < 4; ++mt)
            af[mt] = *(const half8*)&As[(wm * 64 + mt * 16 + l15) * 32 + q * 8];
#pragma unroll
        for (int nt = 0; nt < 4; ++nt)
            bf[nt] = *(const half8*)&Bs[(q * 128 + we * 64 + nt * 16 + l15) * 8];
#pragma unroll
        for (int mt = 0; mt < 4; ++mt)
#pragma unroll
            for (int nt = 0; nt < 4; ++nt)
                acc[mt][nt] = __builtin_amdgcn_mfma_f32_16x16x32_f16(
                    af[mt], bf[nt], acc[mt][nt], 0, 0, 0);
        __syncthreads();
    }

    // ---- epilogue: tanh(c + dec) * vt, reduce over this block's 128 cols ----
    const int b = mtile >> 4;
    float vtv[4], dcv[4];
#pragma unroll
    for (int nt = 0; nt < 4; ++nt) {
        int e = et * 128 + we * 64 + nt * 16 + l15;
        vtv[nt] = vt[e];
        dcv[nt] = dec[b * Dd + e];
    }
#pragma unroll
    for (int mt = 0; mt < 4; ++mt) {
#pragma unroll
        for (int r = 0; r < 4; ++r) {
            float s = 0.f;
#pragma unroll
            for (int nt = 0; nt < 4; ++nt) {
                float x = acc[mt][nt][r] + dcv[nt];
                float ex = __expf(2.f * x);
                float th = 1.f - 2.f * __builtin_amdgcn_rcpf(ex + 1.f);
                s += th * vtv[nt];
            }
#pragma unroll
            for (int off = 1; off < 16; off <<= 1) s += __shfl_xor(s, off, 16);
            if (l15 == 0) usum[we][wm * 64 + mt * 16 + q * 4 + r] = s;
        }
    }
    __syncthreads();
    if (tid < 128)
        u_part[(size_t)et * M + (size_t)mtile * 128 + tid] = usum[0][tid] + usum[1][tid];
}

// ---------------------------------------------------------------------------
// Kernel 3 (fallback): f32 A with in-loop convert (if ws too small).
// ---------------------------------------------------------------------------
__global__ __launch_bounds__(256) void gemm_fused_f32(
    const float* __restrict__ A, const _Float16* __restrict__ W1TT,
    const float* __restrict__ dec, const float* __restrict__ vt,
    float* __restrict__ u_part)
{
    __shared__ _Float16 As2[4 * 128 * 8];
    __shared__ _Float16 Bs2[512 * 8];
    __shared__ float usum[2][128];

    const int et = blockIdx.x, mtile = blockIdx.y;
    const int tid = threadIdx.x;
    const int lane = tid & 63, wid = tid >> 6;
    const int wm = wid & 1, we = wid >> 1;
    const int q = lane >> 4, l15 = lane & 15;
    f32x4 acc[4][4] = {};

    const int arow = tid >> 1, khalf = tid & 1;
    const float* aptr = A + (size_t)(mtile * 128 + arow) * Dd + khalf * 16;
    const int q0 = khalf * 2;
    const _Float16* bbase = W1TT + (size_t)et * 32 * 4096
                            + ((size_t)(wid * 2) * 64 + lane) * 8;
    _Float16* bdst0 = &Bs2[(wid * 2 + 0) * 64 * 8];
    _Float16* bdst1 = &Bs2[(wid * 2 + 1) * 64 * 8];

#pragma unroll 1
    for (int kt = 0; kt < 32; ++kt) {
        const _Float16* bk = bbase + (size_t)kt * 4096;
        __builtin_amdgcn_global_load_lds((const GLOBAL_AS void*)bk,
                                         (LDS_AS void*)bdst0, 16, 0, 0);
        __builtin_amdgcn_global_load_lds((const GLOBAL_AS void*)(bk + 64 * 8),
                                         (LDS_AS void*)bdst1, 16, 0, 0);
        const float4* ap = (const float4*)(aptr + kt * 32);
        float4 f0 = ap[0], f1 = ap[1], f2 = ap[2], f3 = ap[3];
        half8 h0, h1;
        {
            pk2 t;
            t = __builtin_amdgcn_cvt_pkrtz(f0.x, f0.y); h0[0] = t[0]; h0[1] = t[1];
            t = __builtin_amdgcn_cvt_pkrtz(f0.z, f0.w); h0[2] = t[0]; h0[3] = t[1];
            t = __builtin_amdgcn_cvt_pkrtz(f1.x, f1.y); h0[4] = t[0]; h0[5] = t[1];
            t = __builtin_amdgcn_cvt_pkrtz(f1.z, f1.w); h0[6] = t[0]; h0[7] = t[1];
            t = __builtin_amdgcn_cvt_pkrtz(f2.x, f2.y); h1[0] = t[0]; h1[1] = t[1];
            t = __builtin_amdgcn_cvt_pkrtz(f2.z, f2.w); h1[2] = t[0]; h1[3] = t[1];
            t = __builtin_amdgcn_cvt_pkrtz(f3.x, f3.y); h1[4] = t[0]; h1[5] = t[1];
            t = __builtin_amdgcn_cvt_pkrtz(f3.z, f3.w); h1[6] = t[0]; h1[7] = t[1];
        }
        *(half8*)&As2[((q0 + 0) * 128 + arow) * 8] = h0;
        *(half8*)&As2[((q0 + 1) * 128 + arow) * 8] = h1;
        __syncthreads();

        half8 af[4], bf[4];
#pragma unroll
        for (int mt = 0; mt < 4; ++mt)
            af[mt] = *(const half8*)&As2[(q * 128 + wm * 64 + mt * 16 + l15) * 8];
#pragma unroll
        for (int nt = 0; nt < 4; ++nt)
            bf[nt] = *(const half8*)&Bs2[(q * 128 + we * 64 + nt * 16 + l15) * 8];
#pragma unroll
        for (int mt = 0; mt < 4; ++mt)
#pragma unroll
            for (int nt = 0; nt < 4; ++nt)
                acc[mt][nt] = __builtin_amdgcn_mfma_f32_16x16x32_f16(
                    af[mt], bf[nt], acc[mt][nt], 0, 0, 0);
        __syncthreads();
    }

    const int b = mtile >> 4;
    float vtv[4], dcv[4];
#pragma unroll
    for (int nt = 0; nt < 4; ++nt) {
        int e = et * 128 + we * 64 + nt * 16 + l15;
        vtv[nt] = vt[e];
        dcv[nt] = dec[b * Dd + e];
    }
#pragma unroll
    for (int mt = 0; mt < 4; ++mt) {
#pragma unroll
        for (int r = 0; r < 4; ++r) {
            float s = 0.f;
#pragma unroll
            for (int nt = 0; nt < 4; ++nt) {
                float x = acc[mt][nt][r] + dcv[nt];
                float ex = __expf(2.f * x);
                float th = 1.f - 2.f * __builtin_amdgcn_rcpf(ex + 1.f);
                s += th * vtv[nt];
            }
#pragma unroll
            for (int off = 1; off < 16; off <<= 1) s += __shfl_xor(s, off, 16);
            if (l15 == 0) usum[we][wm * 64 + mt * 16 + q * 4 + r] = s;
        }
    }
    __syncthreads();
    if (tid < 128)
        u_part[(size_t)et * M + (size_t)mtile * 128 + tid] = usum[0][tid] + usum[1][tid];
}

// ---------------------------------------------------------------------------
// Kernel 4: masked log-softmax over N=2048 per batch row.
// ---------------------------------------------------------------------------
__global__ void softmax_k(const float* __restrict__ up, const int* __restrict__ mask,
                          float* __restrict__ out) {
    __shared__ float red[8];
    int b = blockIdx.x, tid = threadIdx.x;
    float l[8];
#pragma unroll
    for (int i = 0; i < 8; ++i) {
        int n = i * 256 + tid;
        float s = up[(size_t)b * Nn + n];
#pragma unroll
        for (int et = 1; et < 8; ++et) s += up[(size_t)et * M + (size_t)b * Nn + n];
        l[i] = s + (mask[b * Nn + n] ? 0.f : -103.278931f);  // ln(2^-149)
    }
    float m = l[0];
#pragma unroll
    for (int i = 1; i < 8; ++i) m = fmaxf(m, l[i]);
#pragma unroll
    for (int o = 32; o >= 1; o >>= 1) m = fmaxf(m, __shfl_xor(m, o, 64));
    if ((tid & 63) == 0) red[tid >> 6] = m;
    __syncthreads();
    m = fmaxf(fmaxf(red[0], red[1]), fmaxf(red[2], red[3]));
    float s = 0.f;
#pragma unroll
    for (int i = 0; i < 8; ++i) s += expf(l[i] - m);
#pragma unroll
    for (int o = 32; o >= 1; o >>= 1) s += __shfl_xor(s, o, 64);
    if ((tid & 63) == 0) red[4 + (tid >> 6)] = s;
    __syncthreads();
    float lse = m + logf(red[4] + red[5] + red[6] + red[7]);
#pragma unroll
    for (int i = 0; i < 8; ++i)
        out[(size_t)b * Nn + i * 256 + tid] = l[i] - lse;
}

// ---------------------------------------------------------------------------
extern "C" void kernel_launch(void* const* d_in, const int* in_sizes, int n_in,
                              void* d_out, int out_size, void* d_ws, size_t ws_size,
                              hipStream_t stream) {
    const float* encoded = (const float*)d_in[0];
    const float* dstate  = (const float*)d_in[1];
    const int*   mask    = (const int*)d_in[2];
    const float* W1      = (const float*)d_in[3];
    const float* W2      = (const float*)d_in[4];
    const float* vt      = (const float*)d_in[5];
    float* out = (float*)d_out;

    // ws layout: u_part (2 MiB) | dec (128 KB) | W1TT (2 MiB) | A_p (128 MiB)
    char* ws = (char*)d_ws;
    float*    u_part = (float*)ws;
    float*    dec    = (float*)(ws + (size_t)8 * M * 4);
    _Float16* W1TT   = (_Float16*)(ws + (size_t)8 * M * 4 + (size_t)Bb * Dd * 4);
    _Float16* A_p    = (_Float16*)(ws + (size_t)8 * M * 4 + (size_t)Bb * Dd * 4
                                   + (size_t)Dd * Dd * 2);
    const size_t needed = (size_t)8 * M * 4 + (size_t)Bb * Dd * 4
                        + (size_t)Dd * Dd * 2 + (size_t)M * Dd * 2;

    prep_w1<<<512, 256, 0, stream>>>(W1, W1TT);
    dec_kernel<<<dim3(32, 16), 256, 0, stream>>>(dstate, W2, dec);
    if (ws_size >= needed) {
        prep_enc<<<32768, 256, 0, stream>>>(encoded, A_p);
        gemm_fused_h<<<4096, 256, 0, stream>>>(A_p, W1TT, dec, vt, u_part);
    } else {
        gemm_fused_f32<<<dim3(8, 512), 256, 0, stream>>>(encoded, W1TT, dec, vt, u_part);
    }
    softmax_k<<<32, 256, 0, stream>>>(u_part, mask, out);
}

// Round 5
// 592.982 us; speedup vs baseline: 1.0492x; 1.0287x over previous
//
#include <hip/hip_runtime.h>

typedef _Float16 half8 __attribute__((ext_vector_type(8)));
typedef __fp16   pk2   __attribute__((ext_vector_type(2)));
typedef float    f32x4 __attribute__((ext_vector_type(4)));

#define GLOBAL_AS __attribute__((address_space(1)))
#define LDS_AS    __attribute__((address_space(3)))

static constexpr int Bb = 32;
static constexpr int Nn = 2048;
static constexpr int Dd = 1024;
static constexpr int M  = Bb * Nn;   // 65536 rows of the big GEMM

// ---------------------------------------------------------------------------
// Kernel 1a: pack W1 (f32 [d][e]) -> tile-ordered f16 W1TT.
// tile t = et*32+kt (8 KB), unit u: q=u>>7,e=u&127 holds W1[kt*32+q*8+j][et*128+e].
// ---------------------------------------------------------------------------
__global__ void prep_w1(const float* __restrict__ W1, _Float16* __restrict__ W1TT) {
    int g = blockIdx.x * 256 + threadIdx.x;   // 131072 units
    int tile = g >> 9;
    int u = g & 511;
    int et = tile >> 5, kt = tile & 31;
    int q = u >> 7, e = u & 127;
    int d0 = kt * 32 + q * 8;
    int col = et * 128 + e;
    half8 h;
#pragma unroll
    for (int j = 0; j < 8; ++j)
        h[j] = (_Float16)W1[(size_t)(d0 + j) * Dd + col];
    *(half8*)(W1TT + (size_t)g * 8) = h;
}

// ---------------------------------------------------------------------------
// Kernel 1b: convert+pack encoded (f32 [m][d]) -> f16 tile order A_p.
// tile t = mtile*32+kt (8 KB = 512 units of 8 f16), unit v: row=v>>2, kc=v&3
// holds A[mtile*128+row][kt*32+kc*8 .. +8]. 16 B/thread, fully coalesced.
// ---------------------------------------------------------------------------
__global__ void prep_enc(const float* __restrict__ A, _Float16* __restrict__ A_p) {
    int g = blockIdx.x * 256 + threadIdx.x;    // 8388608 units
    int tile = g >> 9;
    int v = g & 511;
    int row = v >> 2, kc = v & 3;
    const float* src = A + ((size_t)(tile >> 5) * 128 + row) * Dd
                         + (tile & 31) * 32 + kc * 8;
    f32x4 f0 = *(const f32x4*)src;
    f32x4 f1 = *(const f32x4*)(src + 4);
    half8 h;
    pk2 t;
    t = __builtin_amdgcn_cvt_pkrtz(f0.x, f0.y); h[0] = t[0]; h[1] = t[1];
    t = __builtin_amdgcn_cvt_pkrtz(f0.z, f0.w); h[2] = t[0]; h[3] = t[1];
    t = __builtin_amdgcn_cvt_pkrtz(f1.x, f1.y); h[4] = t[0]; h[5] = t[1];
    t = __builtin_amdgcn_cvt_pkrtz(f1.z, f1.w); h[6] = t[0]; h[7] = t[1];
    *(half8*)(A_p + (size_t)g * 8) = h;
}

// ---------------------------------------------------------------------------
// Kernel 2: dec[b][e] = decoder_state[b] @ W2   (32x1024)
// ---------------------------------------------------------------------------
__global__ void dec_kernel(const float* __restrict__ ds, const float* __restrict__ W2,
                           float* __restrict__ dec) {
    __shared__ float part[4][64];
    int b = blockIdx.x, ech = blockIdx.y;
    int tid = threadIdx.x;
    int e = ech * 64 + (tid & 63);
    int dc = tid >> 6;
    float acc = 0.f;
#pragma unroll 4
    for (int d = dc * 256; d < dc * 256 + 256; ++d)
        acc += ds[b * Dd + d] * W2[(size_t)d * Dd + e];
    part[dc][tid & 63] = acc;
    __syncthreads();
    if (tid < 64)
        dec[b * Dd + e] = part[0][tid] + part[1][tid] + part[2][tid] + part[3][tid];
}

// ---------------------------------------------------------------------------
// Kernel 3 (fast path): software-pipelined GEMM, double-buffered LDS,
// raw s_barrier + manual s_waitcnt vmcnt(4) so next-iter global_load_lds
// stay in flight across the barrier (AITER-style; never vmcnt(0) mid-loop).
// XCD swizzle: et=(g>>3)&7, mtile=(g&7)+8*(g>>6)  (same-mtile group on 1 XCD).
// ---------------------------------------------------------------------------
__global__ __launch_bounds__(256) void gemm_fused_h(
    const _Float16* __restrict__ A_p,   // tile-packed f16 encoded
    const _Float16* __restrict__ W1TT,  // tile-packed f16 W1
    const float* __restrict__ dec,
    const float* __restrict__ vt,
    float* __restrict__ u_part)         // [8][65536]
{
    __shared__ _Float16 As[2][4096];    // 2 x 8 KB
    __shared__ _Float16 Bs[2][4096];    // 2 x 8 KB
    __shared__ float usum[2][128];

    const int g = blockIdx.x;           // 0..4095
    const int et = (g >> 3) & 7;
    const int mtile = (g & 7) + ((g >> 6) << 3);
    const int tid = threadIdx.x;
    const int lane = tid & 63, wid = tid >> 6;
    const int wm = wid & 1, we = wid >> 1;
    const int q = lane >> 4, l15 = lane & 15;

    f32x4 acc[4][4] = {};

    // ---- epilogue operands loaded BEFORE the pipeline (keeps vmcnt clean) ----
    const int b = mtile >> 4;
    float vtv[4], dcv[4];
#pragma unroll
    for (int nt = 0; nt < 4; ++nt) {
        int e = et * 128 + we * 64 + nt * 16 + l15;
        vtv[nt] = vt[e];
        dcv[nt] = dec[b * Dd + e];
    }
    asm volatile("s_waitcnt vmcnt(0)" ::: "memory");   // counter now clean

    // staging: wave wid, call c in {0,1}: unit = (wid*2+c)*64 + lane (16 B each)
    const _Float16* abase = A_p + (size_t)mtile * 32 * 4096
                            + ((size_t)(wid * 2) * 64 + lane) * 8;
    const _Float16* bbase = W1TT + (size_t)et * 32 * 4096
                            + ((size_t)(wid * 2) * 64 + lane) * 8;
    _Float16* adst[2] = { &As[0][(wid * 2) * 64 * 8], &As[1][(wid * 2) * 64 * 8] };
    _Float16* bdst[2] = { &Bs[0][(wid * 2) * 64 * 8], &Bs[1][(wid * 2) * 64 * 8] };

    auto issue = [&](int kt) {
        const _Float16* ak = abase + (size_t)kt * 4096;
        const _Float16* bk = bbase + (size_t)kt * 4096;
        const int s = kt & 1;
        __builtin_amdgcn_global_load_lds((const GLOBAL_AS void*)ak,
                                         (LDS_AS void*)adst[s], 16, 0, 0);
        __builtin_amdgcn_global_load_lds((const GLOBAL_AS void*)(ak + 512),
                                         (LDS_AS void*)(adst[s] + 512), 16, 0, 0);
        __builtin_amdgcn_global_load_lds((const GLOBAL_AS void*)bk,
                                         (LDS_AS void*)bdst[s], 16, 0, 0);
        __builtin_amdgcn_global_load_lds((const GLOBAL_AS void*)(bk + 512),
                                         (LDS_AS void*)(bdst[s] + 512), 16, 0, 0);
    };

    issue(0);   // prologue: buffer 0 in flight (vmcnt=4)

#pragma unroll 1
    for (int kt = 0; kt < 32; ++kt) {
        const int s = kt & 1;
        if (kt < 31) {
            issue(kt + 1);                                   // in flight: 8
            asm volatile("s_waitcnt vmcnt(4)" ::: "memory"); // kt's 4 landed
        } else {
            asm volatile("s_waitcnt vmcnt(0)" ::: "memory");
        }
        asm volatile("s_barrier" ::: "memory");              // all waves: kt ready

        half8 af[4], bf[4];
#pragma unroll
        for (int mt = 0; mt < 4; ++mt)
            af[mt] = *(const half8*)&As[s][(wm * 64 + mt * 16 + l15) * 32 + q * 8];
#pragma unroll
        for (int nt = 0; nt < 4; ++nt)
            bf[nt] = *(const half8*)&Bs[s][(q * 128 + we * 64 + nt * 16 + l15) * 8];
#pragma unroll
        for (int mt = 0; mt < 4; ++mt)
#pragma unroll
            for (int nt = 0; nt < 4; ++nt)
                acc[mt][nt] = __builtin_amdgcn_mfma_f32_16x16x32_f16(
                    af[mt], bf[nt], acc[mt][nt], 0, 0, 0);

        asm volatile("s_waitcnt lgkmcnt(0)" ::: "memory");   // ds_reads retired
        asm volatile("s_barrier" ::: "memory");              // buf[s] safe to refill
    }

    // ---- epilogue: tanh(c + dec) * vt, reduce over this block's 128 cols ----
#pragma unroll
    for (int mt = 0; mt < 4; ++mt) {
#pragma unroll
        for (int r = 0; r < 4; ++r) {
            float s = 0.f;
#pragma unroll
            for (int nt = 0; nt < 4; ++nt) {
                float x = acc[mt][nt][r] + dcv[nt];
                float ex = __expf(2.f * x);
                float th = 1.f - 2.f * __builtin_amdgcn_rcpf(ex + 1.f);
                s += th * vtv[nt];
            }
#pragma unroll
            for (int off = 1; off < 16; off <<= 1) s += __shfl_xor(s, off, 16);
            if (l15 == 0) usum[we][wm * 64 + mt * 16 + q * 4 + r] = s;
        }
    }
    __syncthreads();
    if (tid < 128)
        u_part[(size_t)et * M + (size_t)mtile * 128 + tid] = usum[0][tid] + usum[1][tid];
}

// ---------------------------------------------------------------------------
// Kernel 3 (fallback): f32 A with in-loop convert (if ws too small).
// ---------------------------------------------------------------------------
__global__ __launch_bounds__(256) void gemm_fused_f32(
    const float* __restrict__ A, const _Float16* __restrict__ W1TT,
    const float* __restrict__ dec, const float* __restrict__ vt,
    float* __restrict__ u_part)
{
    __shared__ _Float16 As2[4 * 128 * 8];
    __shared__ _Float16 Bs2[512 * 8];
    __shared__ float usum[2][128];

    const int et = blockIdx.x, mtile = blockIdx.y;
    const int tid = threadIdx.x;
    const int lane = tid & 63, wid = tid >> 6;
    const int wm = wid & 1, we = wid >> 1;
    const int q = lane >> 4, l15 = lane & 15;
    f32x4 acc[4][4] = {};

    const int arow = tid >> 1, khalf = tid & 1;
    const float* aptr = A + (size_t)(mtile * 128 + arow) * Dd + khalf * 16;
    const int q0 = khalf * 2;
    const _Float16* bbase = W1TT + (size_t)et * 32 * 4096
                            + ((size_t)(wid * 2) * 64 + lane) * 8;
    _Float16* bdst0 = &Bs2[(wid * 2 + 0) * 64 * 8];
    _Float16* bdst1 = &Bs2[(wid * 2 + 1) * 64 * 8];

#pragma unroll 1
    for (int kt = 0; kt < 32; ++kt) {
        const _Float16* bk = bbase + (size_t)kt * 4096;
        __builtin_amdgcn_global_load_lds((const GLOBAL_AS void*)bk,
                                         (LDS_AS void*)bdst0, 16, 0, 0);
        __builtin_amdgcn_global_load_lds((const GLOBAL_AS void*)(bk + 512),
                                         (LDS_AS void*)bdst1, 16, 0, 0);
        const float4* ap = (const float4*)(aptr + kt * 32);
        float4 f0 = ap[0], f1 = ap[1], f2 = ap[2], f3 = ap[3];
        half8 h0, h1;
        {
            pk2 t;
            t = __builtin_amdgcn_cvt_pkrtz(f0.x, f0.y); h0[0] = t[0]; h0[1] = t[1];
            t = __builtin_amdgcn_cvt_pkrtz(f0.z, f0.w); h0[2] = t[0]; h0[3] = t[1];
            t = __builtin_amdgcn_cvt_pkrtz(f1.x, f1.y); h0[4] = t[0]; h0[5] = t[1];
            t = __builtin_amdgcn_cvt_pkrtz(f1.z, f1.w); h0[6] = t[0]; h0[7] = t[1];
            t = __builtin_amdgcn_cvt_pkrtz(f2.x, f2.y); h1[0] = t[0]; h1[1] = t[1];
            t = __builtin_amdgcn_cvt_pkrtz(f2.z, f2.w); h1[2] = t[0]; h1[3] = t[1];
            t = __builtin_amdgcn_cvt_pkrtz(f3.x, f3.y); h1[4] = t[0]; h1[5] = t[1];
            t = __builtin_amdgcn_cvt_pkrtz(f3.z, f3.w); h1[6] = t[0]; h1[7] = t[1];
        }
        *(half8*)&As2[((q0 + 0) * 128 + arow) * 8] = h0;
        *(half8*)&As2[((q0 + 1) * 128 + arow) * 8] = h1;
        __syncthreads();

        half8 af[4], bf[4];
#pragma unroll
        for (int mt = 0; mt < 4; ++mt)
            af[mt] = *(const half8*)&As2[(q * 128 + wm * 64 + mt * 16 + l15) * 8];
#pragma unroll
        for (int nt = 0; nt < 4; ++nt)
            bf[nt] = *(const half8*)&Bs2[(q * 128 + we * 64 + nt * 16 + l15) * 8];
#pragma unroll
        for (int mt = 0; mt < 4; ++mt)
#pragma unroll
            for (int nt = 0; nt < 4; ++nt)
                acc[mt][nt] = __builtin_amdgcn_mfma_f32_16x16x32_f16(
                    af[mt], bf[nt], acc[mt][nt], 0, 0, 0);
        __syncthreads();
    }

    const int b = mtile >> 4;
    float vtv[4], dcv[4];
#pragma unroll
    for (int nt = 0; nt < 4; ++nt) {
        int e = et * 128 + we * 64 + nt * 16 + l15;
        vtv[nt] = vt[e];
        dcv[nt] = dec[b * Dd + e];
    }
#pragma unroll
    for (int mt = 0; mt < 4; ++mt) {
#pragma unroll
        for (int r = 0; r < 4; ++r) {
            float s = 0.f;
#pragma unroll
            for (int nt = 0; nt < 4; ++nt) {
                float x = acc[mt][nt][r] + dcv[nt];
                float ex = __expf(2.f * x);
                float th = 1.f - 2.f * __builtin_amdgcn_rcpf(ex + 1.f);
                s += th * vtv[nt];
            }
#pragma unroll
            for (int off = 1; off < 16; off <<= 1) s += __shfl_xor(s, off, 16);
            if (l15 == 0) usum[we][wm * 64 + mt * 16 + q * 4 + r] = s;
        }
    }
    __syncthreads();
    if (tid < 128)
        u_part[(size_t)et * M + (size_t)mtile * 128 + tid] = usum[0][tid] + usum[1][tid];
}

// ---------------------------------------------------------------------------
// Kernel 4: masked log-softmax over N=2048 per batch row.
// ---------------------------------------------------------------------------
__global__ void softmax_k(const float* __restrict__ up, const int* __restrict__ mask,
                          float* __restrict__ out) {
    __shared__ float red[8];
    int b = blockIdx.x, tid = threadIdx.x;
    float l[8];
#pragma unroll
    for (int i = 0; i < 8; ++i) {
        int n = i * 256 + tid;
        float s = up[(size_t)b * Nn + n];
#pragma unroll
        for (int et = 1; et < 8; ++et) s += up[(size_t)et * M + (size_t)b * Nn + n];
        l[i] = s + (mask[b * Nn + n] ? 0.f : -103.278931f);  // ln(2^-149)
    }
    float m = l[0];
#pragma unroll
    for (int i = 1; i < 8; ++i) m = fmaxf(m, l[i]);
#pragma unroll
    for (int o = 32; o >= 1; o >>= 1) m = fmaxf(m, __shfl_xor(m, o, 64));
    if ((tid & 63) == 0) red[tid >> 6] = m;
    __syncthreads();
    m = fmaxf(fmaxf(red[0], red[1]), fmaxf(red[2], red[3]));
    float s = 0.f;
#pragma unroll
    for (int i = 0; i < 8; ++i) s += expf(l[i] - m);
#pragma unroll
    for (int o = 32; o >= 1; o >>= 1) s += __shfl_xor(s, o, 64);
    if ((tid & 63) == 0) red[4 + (tid >> 6)] = s;
    __syncthreads();
    float lse = m + logf(red[4] + red[5] + red[6] + red[7]);
#pragma unroll
    for (int i = 0; i < 8; ++i)
        out[(size_t)b * Nn + i * 256 + tid] = l[i] - lse;
}

// ---------------------------------------------------------------------------
extern "C" void kernel_launch(void* const* d_in, const int* in_sizes, int n_in,
                              void* d_out, int out_size, void* d_ws, size_t ws_size,
                              hipStream_t stream) {
    const float* encoded = (const float*)d_in[0];
    const float* dstate  = (const float*)d_in[1];
    const int*   mask    = (const int*)d_in[2];
    const float* W1      = (const float*)d_in[3];
    const float* W2      = (const float*)d_in[4];
    const float* vt      = (const float*)d_in[5];
    float* out = (float*)d_out;

    // ws layout: u_part (2 MiB) | dec (128 KB) | W1TT (2 MiB) | A_p (128 MiB)
    char* ws = (char*)d_ws;
    float*    u_part = (float*)ws;
    float*    dec    = (float*)(ws + (size_t)8 * M * 4);
    _Float16* W1TT   = (_Float16*)(ws + (size_t)8 * M * 4 + (size_t)Bb * Dd * 4);
    _Float16* A_p    = (_Float16*)(ws + (size_t)8 * M * 4 + (size_t)Bb * Dd * 4
                                   + (size_t)Dd * Dd * 2);
    const size_t needed = (size_t)8 * M * 4 + (size_t)Bb * Dd * 4
                        + (size_t)Dd * Dd * 2 + (size_t)M * Dd * 2;

    prep_w1<<<512, 256, 0, stream>>>(W1, W1TT);
    dec_kernel<<<dim3(32, 16), 256, 0, stream>>>(dstate, W2, dec);
    if (ws_size >= needed) {
        prep_enc<<<32768, 256, 0, stream>>>(encoded, A_p);
        gemm_fused_h<<<4096, 256, 0, stream>>>(A_p, W1TT, dec, vt, u_part);
    } else {
        gemm_fused_f32<<<dim3(8, 512), 256, 0, stream>>>(encoded, W1TT, dec, vt, u_part);
    }
    softmax_k<<<32, 256, 0, stream>>>(u_part, mask, out);
}